// Round 1
// baseline (358.674 us; speedup 1.0000x reference)
//
#include <hip/hip_runtime.h>

#define MROWS 8192
#define NPTS  131072
#define CB    16
#define CC    128

// ---------------- kernel 1: skin_fea = qcf @ W_stretch + b_stretch ----------
__global__ __launch_bounds__(256) void skin_kernel(
    const float* __restrict__ qcf, const float* __restrict__ Ws,
    const float* __restrict__ bs, float* __restrict__ skin)
{
    int t = blockIdx.x * 256 + threadIdx.x;   // 8192*128 threads
    int m = t >> 7, d = t & 127;
    float acc = bs[d];
    const float* q = qcf + m * CB;
#pragma unroll
    for (int c = 0; c < CB; ++c) acc = fmaf(q[c], Ws[c * CC + d], acc);
    skin[t] = acc;
}

// ---------------- kernel 2: fused gather + interp + MLP ---------------------
// block = 256 threads = 4 waves; each wave processes 2 points per iteration.
// LDS: W1 packed as float2 (d, d+64) per channel-row; W2 row-major.
__global__ __launch_bounds__(256) void decoder_kernel(
    const int*   __restrict__ didx, const float* __restrict__ dwin,
    const float* __restrict__ bones, const float* __restrict__ skin,
    const float* __restrict__ W1, const float* __restrict__ b1,
    const float* __restrict__ W2, const float* __restrict__ b2,
    const float* __restrict__ W3, const float* __restrict__ b3,
    float* __restrict__ out)
{
    __shared__ float sW1[131 * 128];   // [c][2*dp + j]  where d = j*64 + dp
    __shared__ float sW2[128 * 32];    // [d][e]
    __shared__ float sb1[128];
    __shared__ float sb2[32];
    __shared__ float sW3[24];
    __shared__ float sb3[3];
    __shared__ float sx[8][132];       // per (wave,point) x / h1 buffer
    __shared__ float sh2[8][32];       // per (wave,point) h2

    const int tid = threadIdx.x;
    for (int i = tid; i < 131 * 128; i += 256) {
        int c = i >> 7, d = i & 127;
        sW1[c * 128 + ((d & 63) << 1) + (d >> 6)] = W1[i];
    }
    for (int i = tid; i < 128 * 32; i += 256) sW2[i] = W2[i];
    if (tid < 128) sb1[tid] = b1[tid];
    if (tid < 32)  sb2[tid] = b2[tid];
    if (tid < 24)  sW3[tid] = W3[tid];
    if (tid < 3)   sb3[tid] = b3[tid];
    __syncthreads();

    const int wave = tid >> 6;
    const int lane = tid & 63;

    for (int p0 = blockIdx.x * 8; p0 < NPTS; p0 += gridDim.x * 8) {
        const int pA = p0 + wave * 2;
        const int pB = pA + 1;

        const float wxA = dwin[pA*3+0], wyA = dwin[pA*3+1], wzA = dwin[pA*3+2];
        const float wxB = dwin[pB*3+0], wyB = dwin[pB*3+1], wzB = dwin[pB*3+2];

        int idxA[8], idxB[8];
#pragma unroll
        for (int k = 0; k < 8; ++k) { idxA[k] = didx[pA*8+k]; idxB[k] = didx[pB*8+k]; }

        // --- inverse-distance weights: lanes 0..7 -> A, lanes 8..15 -> B ----
        float wn;
        {
            int grp = (lane >> 3) & 1;
            int k = lane & 7;
            int id = grp ? idxB[k] : idxA[k];
            float bx = bones[id*3+0], by = bones[id*3+1], bz = bones[id*3+2];
            float rx = (grp ? wxB : wxA) - bx;
            float ry = (grp ? wyB : wyA) - by;
            float rz = (grp ? wzB : wzA) - bz;
            float dist = sqrtf(fmaf(rx,rx, fmaf(ry,ry, rz*rz)) + 1e-8f);
            float w = 1.0f / (dist + 1e-8f);
            float s = w;
            s += __shfl_xor(s, 1);
            s += __shfl_xor(s, 2);
            s += __shfl_xor(s, 4);
            wn = w / s;
        }
        float wA[8], wB[8];
#pragma unroll
        for (int k = 0; k < 8; ++k) {
            wA[k] = __shfl(wn, k);
            wB[k] = __shfl(wn, 8 + k);
        }

        // --- interp: lane owns channels (lane, lane+64) for both points ----
        float a00 = 0.f, a01 = 0.f, a10 = 0.f, a11 = 0.f;
#pragma unroll
        for (int k = 0; k < 8; ++k) {
            const float* rA = skin + idxA[k] * CC;
            const float* rB = skin + idxB[k] * CC;
            a00 = fmaf(wA[k], rA[lane],      a00);
            a01 = fmaf(wA[k], rA[lane + 64], a01);
            a10 = fmaf(wB[k], rB[lane],      a10);
            a11 = fmaf(wB[k], rB[lane + 64], a11);
        }
        float* xA = sx[wave*2 + 0];
        float* xB = sx[wave*2 + 1];
        xA[lane] = a00; xA[lane+64] = a01;
        xB[lane] = a10; xB[lane+64] = a11;
        __syncthreads();

        // --- layer 1: h1[d] = relu(b1[d] + sum_c x[c] W1[c][d]) -------------
        float hA0 = sb1[lane], hA1 = sb1[lane+64];
        float hB0 = hA0,       hB1 = hA1;
        const float2* Wp  = (const float2*)sW1;
        const float4* xA4 = (const float4*)xA;
        const float4* xB4 = (const float4*)xB;
#pragma unroll 4
        for (int c4 = 0; c4 < 32; ++c4) {
            const float4 xa = xA4[c4];
            const float4 xb = xB4[c4];
            const float2 q0 = Wp[(c4*4+0)*64 + lane];
            const float2 q1 = Wp[(c4*4+1)*64 + lane];
            const float2 q2 = Wp[(c4*4+2)*64 + lane];
            const float2 q3 = Wp[(c4*4+3)*64 + lane];
            hA0 = fmaf(xa.x, q0.x, hA0); hA1 = fmaf(xa.x, q0.y, hA1);
            hB0 = fmaf(xb.x, q0.x, hB0); hB1 = fmaf(xb.x, q0.y, hB1);
            hA0 = fmaf(xa.y, q1.x, hA0); hA1 = fmaf(xa.y, q1.y, hA1);
            hB0 = fmaf(xb.y, q1.x, hB0); hB1 = fmaf(xb.y, q1.y, hB1);
            hA0 = fmaf(xa.z, q2.x, hA0); hA1 = fmaf(xa.z, q2.y, hA1);
            hB0 = fmaf(xb.z, q2.x, hB0); hB1 = fmaf(xb.z, q2.y, hB1);
            hA0 = fmaf(xa.w, q3.x, hA0); hA1 = fmaf(xa.w, q3.y, hA1);
            hB0 = fmaf(xb.w, q3.x, hB0); hB1 = fmaf(xb.w, q3.y, hB1);
        }
        {   // c = 128..130: window components (in registers, wave-uniform)
            const float2 q0 = Wp[128*64 + lane];
            const float2 q1 = Wp[129*64 + lane];
            const float2 q2 = Wp[130*64 + lane];
            hA0 = fmaf(wxA, q0.x, hA0); hA1 = fmaf(wxA, q0.y, hA1);
            hB0 = fmaf(wxB, q0.x, hB0); hB1 = fmaf(wxB, q0.y, hB1);
            hA0 = fmaf(wyA, q1.x, hA0); hA1 = fmaf(wyA, q1.y, hA1);
            hB0 = fmaf(wyB, q1.x, hB0); hB1 = fmaf(wyB, q1.y, hB1);
            hA0 = fmaf(wzA, q2.x, hA0); hA1 = fmaf(wzA, q2.y, hA1);
            hB0 = fmaf(wzB, q2.x, hB0); hB1 = fmaf(wzB, q2.y, hB1);
        }
        hA0 = fmaxf(hA0, 0.f); hA1 = fmaxf(hA1, 0.f);
        hB0 = fmaxf(hB0, 0.f); hB1 = fmaxf(hB1, 0.f);

        xA[lane] = hA0; xA[lane+64] = hA1;
        xB[lane] = hB0; xB[lane+64] = hB1;
        __syncthreads();

        // --- layer 2: h2[e] = relu(b2[e] + sum_d h1[d] W2[d][e]) ------------
        const int e    = lane & 31;
        const int half = lane >> 5;
        float accA = 0.f, accB = 0.f;
        const float4* hA4 = (const float4*)(xA + half*64);
        const float4* hB4 = (const float4*)(xB + half*64);
#pragma unroll 4
        for (int d4 = 0; d4 < 16; ++d4) {
            const float4 ha = hA4[d4];
            const float4 hb = hB4[d4];
            const int d = half*64 + d4*4;
            const float v0 = sW2[(d+0)*32 + e];
            const float v1 = sW2[(d+1)*32 + e];
            const float v2 = sW2[(d+2)*32 + e];
            const float v3 = sW2[(d+3)*32 + e];
            accA = fmaf(ha.x, v0, accA); accB = fmaf(hb.x, v0, accB);
            accA = fmaf(ha.y, v1, accA); accB = fmaf(hb.y, v1, accB);
            accA = fmaf(ha.z, v2, accA); accB = fmaf(hb.z, v2, accB);
            accA = fmaf(ha.w, v3, accA); accB = fmaf(hb.w, v3, accB);
        }
        accA += __shfl_xor(accA, 32);
        accB += __shfl_xor(accB, 32);
        const float h2A = fmaxf(accA + sb2[e], 0.f);
        const float h2B = fmaxf(accB + sb2[e], 0.f);

        if (lane < 32) sh2[wave*2 + 0][lane]      = h2A;
        else           sh2[wave*2 + 1][lane - 32] = h2B;
        __syncthreads();

        // --- layer 3 + residual: 24 outputs (2 points x 4 r x 3 o) ----------
        if (lane < 24) {
            const int pt = lane / 12;      // 0=A, 1=B
            const int q  = lane % 12;      // r*3 + o
            const int r  = q / 3;
            const int o  = q - r*3;
            const float* h2 = sh2[wave*2 + pt];
            float acc = sb3[o];
#pragma unroll
            for (int f = 0; f < 8; ++f) acc = fmaf(h2[r*8 + f], sW3[f*3 + o], acc);
            const float w0  = pt ? wxB : wxA;
            const float w1v = pt ? wyB : wyA;
            const float w2v = pt ? wzB : wzA;
            const float wo  = (o == 0) ? w0 : ((o == 1) ? w1v : w2v);
            const int pp = pt ? pB : pA;
            out[pp*12 + q] = wo + acc;
        }
    }
}

extern "C" void kernel_launch(void* const* d_in, const int* in_sizes, int n_in,
                              void* d_out, int out_size, void* d_ws, size_t ws_size,
                              hipStream_t stream) {
    const float* qcf   = (const float*)d_in[0];
    const int*   didx  = (const int*)  d_in[1];
    const float* dwin  = (const float*)d_in[2];
    const float* bones = (const float*)d_in[3];
    // d_in[4] = K (always 8)
    const float* Ws = (const float*)d_in[5];
    const float* bs = (const float*)d_in[6];
    const float* W1 = (const float*)d_in[7];
    const float* b1 = (const float*)d_in[8];
    const float* W2 = (const float*)d_in[9];
    const float* b2 = (const float*)d_in[10];
    const float* W3 = (const float*)d_in[11];
    const float* b3 = (const float*)d_in[12];
    float* out  = (float*)d_out;
    float* skin = (float*)d_ws;   // 8192*128 floats = 4 MB

    hipLaunchKernelGGL(skin_kernel, dim3((MROWS*CC)/256), dim3(256), 0, stream,
                       qcf, Ws, bs, skin);
    hipLaunchKernelGGL(decoder_kernel, dim3(512), dim3(256), 0, stream,
                       didx, dwin, bones, skin, W1, b1, W2, b2, W3, b3, out);
}

// Round 2
// 32.347 us; speedup vs baseline: 11.0885x; 11.0885x over previous
//
#include <hip/hip_runtime.h>

typedef __attribute__((ext_vector_type(8))) short short8;   // 8 bf16 (4 VGPRs)
typedef __attribute__((ext_vector_type(4))) float f32x4;    // MFMA acc

#define NPTS 131072

__device__ inline unsigned short f2bf(float f) {
    unsigned u = __float_as_uint(f);
    u = (u + 0x7FFFu + ((u >> 16) & 1u)) >> 16;   // RNE
    return (unsigned short)u;
}

// ---------------- prep: fold Ws@W1 -> Weff (bf16, transposed), W2T, beff ----
__global__ __launch_bounds__(256) void prep_kernel(
    const float* __restrict__ Ws, const float* __restrict__ bs,
    const float* __restrict__ W1, const float* __restrict__ b1,
    const float* __restrict__ W2,
    unsigned short* __restrict__ w1t, unsigned short* __restrict__ w2t,
    float* __restrict__ beff)
{
    int t = blockIdx.x * 256 + threadIdx.x;
    if (t < 4096) {                       // W1effT[e][k], k: 0..15 qcf, 16..18 win, rest 0
        int e = t >> 5, k = t & 31;
        float v = 0.f;
        if (k < 16) {
            for (int d = 0; d < 128; ++d) v = fmaf(Ws[k*128 + d], W1[d*128 + e], v);
        } else if (k < 19) {
            v = W1[(128 + (k - 16))*128 + e];
        }
        w1t[e*32 + k] = f2bf(v);
    } else if (t < 8192) {                // W2T[e][k] = W2[k][e]
        int t2 = t - 4096;
        int e = t2 >> 7, k = t2 & 127;
        w2t[e*128 + k] = f2bf(W2[k*32 + e]);
    } else if (t < 8320) {                // beff[e] = b1[e] + bs @ W1[0:128]
        int e = t - 8192;
        float v = b1[e];
        for (int d = 0; d < 128; ++d) v = fmaf(bs[d], W1[d*128 + e], v);
        beff[e] = v;
    }
}

// ---------------- main fused kernel ----------------------------------------
// Per-wave-private LDS region (no __syncthreads in main loop):
//   X   @0     : 16 pts x 40 bf16 (stride 80 B)   = 1280 B
//   H1  @1280  : 16 pts x 136 bf16 (stride 272 B) = 4352 B
//   H2  @5632  : 16 pts x 33 f32                  = 2112 B
//   Wb  @7744  : 16x8 f32                         = 512 B
//   Ib  @8256  : 16x8 int                         = 512 B
#define WREG 8768

__global__ __launch_bounds__(256, 2) void decoder_kernel(
    const float* __restrict__ qcf, const int* __restrict__ didx,
    const float* __restrict__ dwin, const float* __restrict__ bones,
    const unsigned short* __restrict__ w1t, const unsigned short* __restrict__ w2t,
    const float* __restrict__ beff, const float* __restrict__ b2,
    const float* __restrict__ W3, const float* __restrict__ b3,
    float* __restrict__ out)
{
    __shared__ unsigned char lds[4 * WREG];
    __shared__ float sW3[27];

    const int tid = threadIdx.x;
    if (tid < 24) sW3[tid] = W3[tid];
    if (tid < 3)  sW3[24 + tid] = b3[tid];
    __syncthreads();

    const int wave = tid >> 6;
    const int lane = tid & 63;
    unsigned char* wbase = lds + wave * WREG;
    unsigned short* Xb  = (unsigned short*)(wbase);
    unsigned short* H1b = (unsigned short*)(wbase + 1280);
    float*          H2b = (float*)(wbase + 5632);
    float*          Wb  = (float*)(wbase + 7744);
    int*            Ib  = (int*)(wbase + 8256);

    const int q4  = lane >> 4;   // quarter-wave
    const int l16 = lane & 15;

    // hoisted B-fragments + biases (wave-invariant)
    short8 W1f[8]; float beffv[8];
#pragma unroll
    for (int dt = 0; dt < 8; ++dt) {
        W1f[dt]   = *(const short8*)(w1t + (dt*16 + l16)*32 + q4*8);
        beffv[dt] = beff[dt*16 + l16];
    }
    short8 W2f[2][4]; float b2v[2];
#pragma unroll
    for (int et = 0; et < 2; ++et) {
        b2v[et] = b2[et*16 + l16];
#pragma unroll
        for (int kt = 0; kt < 4; ++kt)
            W2f[et][kt] = *(const short8*)(w2t + (et*16 + l16)*128 + kt*32 + q4*8);
    }

    const int gw = blockIdx.x * 4 + wave;

    for (int it = 0; it < 4; ++it) {
        const int base = gw * 64 + it * 16;   // 16 points per wave-iter

        // ---- IDW weights: 2 passes x (8 pts x 8 k) -------------------------
#pragma unroll
        for (int ph = 0; ph < 2; ++ph) {
            const int pl = ph*8 + (lane >> 3);
            const int k  = lane & 7;
            const int p  = base + pl;
            const int id = didx[p*8 + k];
            const float bx = bones[id*3+0], by = bones[id*3+1], bz = bones[id*3+2];
            const float rx = dwin[p*3+0] - bx;
            const float ry = dwin[p*3+1] - by;
            const float rz = dwin[p*3+2] - bz;
            const float dist = sqrtf(fmaf(rx,rx, fmaf(ry,ry, fmaf(rz,rz, 1e-8f))));
            const float w = 1.0f / (dist + 1e-8f);
            float s = w;
            s += __shfl_xor(s, 1);
            s += __shfl_xor(s, 2);
            s += __shfl_xor(s, 4);
            Wb[pl*8 + k] = w / s;
            Ib[pl*8 + k] = id;
        }

        // ---- interp in qcf(16) space: 4 passes x 4 pts, build X bf16 -------
#pragma unroll
        for (int ps = 0; ps < 4; ++ps) {
            const int pl = ps*4 + q4;
            const int4   i0 = *(const int4*)(Ib + pl*8);
            const int4   i1 = *(const int4*)(Ib + pl*8 + 4);
            const float4 w0 = *(const float4*)(Wb + pl*8);
            const float4 w1 = *(const float4*)(Wb + pl*8 + 4);
            float acc = 0.f;
            acc = fmaf(w0.x, qcf[i0.x*16 + l16], acc);
            acc = fmaf(w0.y, qcf[i0.y*16 + l16], acc);
            acc = fmaf(w0.z, qcf[i0.z*16 + l16], acc);
            acc = fmaf(w0.w, qcf[i0.w*16 + l16], acc);
            acc = fmaf(w1.x, qcf[i1.x*16 + l16], acc);
            acc = fmaf(w1.y, qcf[i1.y*16 + l16], acc);
            acc = fmaf(w1.z, qcf[i1.z*16 + l16], acc);
            acc = fmaf(w1.w, qcf[i1.w*16 + l16], acc);
            Xb[pl*40 + l16] = f2bf(acc);
            float wv = 0.f;
            if (l16 < 3) wv = dwin[(base + pl)*3 + l16];
            Xb[pl*40 + 16 + l16] = f2bf(wv);        // k=16..18 win, 19..31 zero
        }

        // ---- layer 1: [16 x 32] @ [32 x 128] via 8 MFMA --------------------
        const short8 a1 = *(const short8*)(Xb + l16*40 + q4*8);
        f32x4 acc1[8];
#pragma unroll
        for (int dt = 0; dt < 8; ++dt) {
            f32x4 c = { beffv[dt], beffv[dt], beffv[dt], beffv[dt] };
            acc1[dt] = __builtin_amdgcn_mfma_f32_16x16x32_bf16(a1, W1f[dt], c, 0, 0, 0);
        }
#pragma unroll
        for (int dt = 0; dt < 8; ++dt) {
#pragma unroll
            for (int r = 0; r < 4; ++r) {
                const float h = fmaxf(acc1[dt][r], 0.f);
                H1b[(q4*4 + r)*136 + dt*16 + l16] = f2bf(h);
            }
        }

        // ---- layer 2: [16 x 128] @ [128 x 32] via 8 MFMA -------------------
        f32x4 acc2[2] = { { b2v[0], b2v[0], b2v[0], b2v[0] },
                          { b2v[1], b2v[1], b2v[1], b2v[1] } };
#pragma unroll
        for (int kt = 0; kt < 4; ++kt) {
            const short8 a2 = *(const short8*)(H1b + l16*136 + kt*32 + q4*8);
            acc2[0] = __builtin_amdgcn_mfma_f32_16x16x32_bf16(a2, W2f[0][kt], acc2[0], 0, 0, 0);
            acc2[1] = __builtin_amdgcn_mfma_f32_16x16x32_bf16(a2, W2f[1][kt], acc2[1], 0, 0, 0);
        }
#pragma unroll
        for (int et = 0; et < 2; ++et) {
#pragma unroll
            for (int r = 0; r < 4; ++r) {
                H2b[(q4*4 + r)*33 + et*16 + l16] = fmaxf(acc2[et][r], 0.f);
            }
        }

        // ---- layer 3 (8->3 x4) + residual + store --------------------------
#pragma unroll
        for (int i3 = 0; i3 < 3; ++i3) {
            const int g  = i3*64 + lane;      // 0..191 = 16 pts x 12
            const int pt = g / 12;
            const int q  = g - pt*12;
            const int r  = q / 3;
            const int o  = q - r*3;
            float acc = sW3[24 + o];
#pragma unroll
            for (int f = 0; f < 8; ++f)
                acc = fmaf(H2b[pt*33 + r*8 + f], sW3[f*3 + o], acc);
            const float wv = dwin[(base + pt)*3 + o];
            out[(size_t)base*12 + g] = wv + acc;
        }
    }
}

extern "C" void kernel_launch(void* const* d_in, const int* in_sizes, int n_in,
                              void* d_out, int out_size, void* d_ws, size_t ws_size,
                              hipStream_t stream) {
    const float* qcf   = (const float*)d_in[0];
    const int*   didx  = (const int*)  d_in[1];
    const float* dwin  = (const float*)d_in[2];
    const float* bones = (const float*)d_in[3];
    // d_in[4] = K (always 8)
    const float* Ws = (const float*)d_in[5];
    const float* bs = (const float*)d_in[6];
    const float* W1 = (const float*)d_in[7];
    const float* b1 = (const float*)d_in[8];
    const float* W2 = (const float*)d_in[9];
    const float* b2 = (const float*)d_in[10];
    const float* W3 = (const float*)d_in[11];
    const float* b3 = (const float*)d_in[12];
    float* out = (float*)d_out;

    unsigned short* w1t  = (unsigned short*)d_ws;                    // 8 KB
    unsigned short* w2t  = (unsigned short*)((char*)d_ws + 8192);    // 8 KB
    float*          beff = (float*)((char*)d_ws + 16384);            // 512 B

    hipLaunchKernelGGL(prep_kernel, dim3(33), dim3(256), 0, stream,
                       Ws, bs, W1, b1, W2, w1t, w2t, beff);
    hipLaunchKernelGGL(decoder_kernel, dim3(512), dim3(256), 0, stream,
                       qcf, didx, dwin, bones, w1t, w2t, beff, b2, W3, b3, out);
}

// Round 4
// 31.428 us; speedup vs baseline: 11.4124x; 1.0292x over previous
//
#include <hip/hip_runtime.h>

typedef __attribute__((ext_vector_type(8))) short short8;   // 8 bf16 (4 VGPRs)
typedef __attribute__((ext_vector_type(4))) float f32x4;    // MFMA acc

#define NPTS 131072

__device__ inline unsigned short f2bf(float f) {
    unsigned u = __float_as_uint(f);
    u = (u + 0x7FFFu + ((u >> 16) & 1u)) >> 16;   // RNE
    return (unsigned short)u;
}

// ---------------- prep: fold Ws@W1 -> Weff (bf16, transposed), W2T, beff ----
__global__ __launch_bounds__(256) void prep_kernel(
    const float* __restrict__ Ws, const float* __restrict__ bs,
    const float* __restrict__ W1, const float* __restrict__ b1,
    const float* __restrict__ W2,
    unsigned short* __restrict__ w1t, unsigned short* __restrict__ w2t,
    float* __restrict__ beff)
{
    int t = blockIdx.x * 256 + threadIdx.x;
    if (t < 4096) {                       // W1effT[e][k], k: 0..15 qcf, 16..18 win, rest 0
        int e = t >> 5, k = t & 31;
        float v = 0.f;
        if (k < 16) {
            for (int d = 0; d < 128; ++d) v = fmaf(Ws[k*128 + d], W1[d*128 + e], v);
        } else if (k < 19) {
            v = W1[(128 + (k - 16))*128 + e];
        }
        w1t[e*32 + k] = f2bf(v);
    } else if (t < 8192) {                // W2T[e][k] = W2[k][e]
        int t2 = t - 4096;
        int e = t2 >> 7, k = t2 & 127;
        w2t[e*128 + k] = f2bf(W2[k*32 + e]);
    } else if (t < 8320) {                // beff[e] = b1[e] + bs @ W1[0:128]
        int e = t - 8192;
        float v = b1[e];
        for (int d = 0; d < 128; ++d) v = fmaf(bs[d], W1[d*128 + e], v);
        beff[e] = v;
    }
}

// ---------------- main fused kernel ----------------------------------------
// Identical body to the round-2 kernel that passed post-timing validation;
// the ONLY change: one 16-point tile per wave (grid 2048) instead of a
// 4-iteration serial loop (grid 512).
// Per-wave-private LDS region (no __syncthreads in main path):
//   X   @0     : 16 pts x 40 bf16 (stride 80 B)   = 1280 B
//   H1  @1280  : 16 pts x 136 bf16 (stride 272 B) = 4352 B
//   H2  @5632  : 16 pts x 33 f32                  = 2112 B
//   Wb  @7744  : 16x8 f32                         = 512 B
//   Ib  @8256  : 16x8 int                         = 512 B
#define WREG 8768

__global__ __launch_bounds__(256, 2) void decoder_kernel(
    const float* __restrict__ qcf, const int* __restrict__ didx,
    const float* __restrict__ dwin, const float* __restrict__ bones,
    const unsigned short* __restrict__ w1t, const unsigned short* __restrict__ w2t,
    const float* __restrict__ beff, const float* __restrict__ b2,
    const float* __restrict__ W3, const float* __restrict__ b3,
    float* __restrict__ out)
{
    __shared__ unsigned char lds[4 * WREG];
    __shared__ float sW3[27];

    const int tid = threadIdx.x;
    if (tid < 24) sW3[tid] = W3[tid];
    if (tid < 3)  sW3[24 + tid] = b3[tid];
    __syncthreads();

    const int wave = tid >> 6;
    const int lane = tid & 63;
    unsigned char* wbase = lds + wave * WREG;
    unsigned short* Xb  = (unsigned short*)(wbase);
    unsigned short* H1b = (unsigned short*)(wbase + 1280);
    float*          H2b = (float*)(wbase + 5632);
    float*          Wb  = (float*)(wbase + 7744);
    int*            Ib  = (int*)(wbase + 8256);

    const int q4  = lane >> 4;   // quarter-wave
    const int l16 = lane & 15;

    // hoisted B-fragments + biases (wave-invariant)
    short8 W1f[8]; float beffv[8];
#pragma unroll
    for (int dt = 0; dt < 8; ++dt) {
        W1f[dt]   = *(const short8*)(w1t + (dt*16 + l16)*32 + q4*8);
        beffv[dt] = beff[dt*16 + l16];
    }
    short8 W2f[2][4]; float b2v[2];
#pragma unroll
    for (int et = 0; et < 2; ++et) {
        b2v[et] = b2[et*16 + l16];
#pragma unroll
        for (int kt = 0; kt < 4; ++kt)
            W2f[et][kt] = *(const short8*)(w2t + (et*16 + l16)*128 + kt*32 + q4*8);
    }

    const int gw   = blockIdx.x * 4 + wave;
    const int base = gw * 16;   // one 16-point tile per wave

    // ---- IDW weights: 2 passes x (8 pts x 8 k) -----------------------------
#pragma unroll
    for (int ph = 0; ph < 2; ++ph) {
        const int pl = ph*8 + (lane >> 3);
        const int k  = lane & 7;
        const int p  = base + pl;
        const int id = didx[p*8 + k];
        const float bx = bones[id*3+0], by = bones[id*3+1], bz = bones[id*3+2];
        const float rx = dwin[p*3+0] - bx;
        const float ry = dwin[p*3+1] - by;
        const float rz = dwin[p*3+2] - bz;
        const float dist = sqrtf(fmaf(rx,rx, fmaf(ry,ry, fmaf(rz,rz, 1e-8f))));
        const float w = 1.0f / (dist + 1e-8f);
        float s = w;
        s += __shfl_xor(s, 1);
        s += __shfl_xor(s, 2);
        s += __shfl_xor(s, 4);
        Wb[pl*8 + k] = w / s;
        Ib[pl*8 + k] = id;
    }

    // ---- interp in qcf(16) space: 4 passes x 4 pts, build X bf16 -----------
#pragma unroll
    for (int ps = 0; ps < 4; ++ps) {
        const int pl = ps*4 + q4;
        const int4   i0 = *(const int4*)(Ib + pl*8);
        const int4   i1 = *(const int4*)(Ib + pl*8 + 4);
        const float4 w0 = *(const float4*)(Wb + pl*8);
        const float4 w1 = *(const float4*)(Wb + pl*8 + 4);
        float acc = 0.f;
        acc = fmaf(w0.x, qcf[i0.x*16 + l16], acc);
        acc = fmaf(w0.y, qcf[i0.y*16 + l16], acc);
        acc = fmaf(w0.z, qcf[i0.z*16 + l16], acc);
        acc = fmaf(w0.w, qcf[i0.w*16 + l16], acc);
        acc = fmaf(w1.x, qcf[i1.x*16 + l16], acc);
        acc = fmaf(w1.y, qcf[i1.y*16 + l16], acc);
        acc = fmaf(w1.z, qcf[i1.z*16 + l16], acc);
        acc = fmaf(w1.w, qcf[i1.w*16 + l16], acc);
        Xb[pl*40 + l16] = f2bf(acc);
        float wv = 0.f;
        if (l16 < 3) wv = dwin[(base + pl)*3 + l16];
        Xb[pl*40 + 16 + l16] = f2bf(wv);        // k=16..18 win, 19..31 zero
    }

    // ---- layer 1: [16 x 32] @ [32 x 128] via 8 MFMA ------------------------
    const short8 a1 = *(const short8*)(Xb + l16*40 + q4*8);
    f32x4 acc1[8];
#pragma unroll
    for (int dt = 0; dt < 8; ++dt) {
        f32x4 c = { beffv[dt], beffv[dt], beffv[dt], beffv[dt] };
        acc1[dt] = __builtin_amdgcn_mfma_f32_16x16x32_bf16(a1, W1f[dt], c, 0, 0, 0);
    }
#pragma unroll
    for (int dt = 0; dt < 8; ++dt) {
#pragma unroll
        for (int r = 0; r < 4; ++r) {
            const float h = fmaxf(acc1[dt][r], 0.f);
            H1b[(q4*4 + r)*136 + dt*16 + l16] = f2bf(h);
        }
    }

    // ---- layer 2: [16 x 128] @ [128 x 32] via 8 MFMA -----------------------
    f32x4 acc2[2] = { { b2v[0], b2v[0], b2v[0], b2v[0] },
                      { b2v[1], b2v[1], b2v[1], b2v[1] } };
#pragma unroll
    for (int kt = 0; kt < 4; ++kt) {
        const short8 a2 = *(const short8*)(H1b + l16*136 + kt*32 + q4*8);
        acc2[0] = __builtin_amdgcn_mfma_f32_16x16x32_bf16(a2, W2f[0][kt], acc2[0], 0, 0, 0);
        acc2[1] = __builtin_amdgcn_mfma_f32_16x16x32_bf16(a2, W2f[1][kt], acc2[1], 0, 0, 0);
    }
#pragma unroll
    for (int et = 0; et < 2; ++et) {
#pragma unroll
        for (int r = 0; r < 4; ++r) {
            H2b[(q4*4 + r)*33 + et*16 + l16] = fmaxf(acc2[et][r], 0.f);
        }
    }

    // ---- layer 3 (8->3 x4) + residual + store ------------------------------
#pragma unroll
    for (int i3 = 0; i3 < 3; ++i3) {
        const int g  = i3*64 + lane;      // 0..191 = 16 pts x 12
        const int pt = g / 12;
        const int q  = g - pt*12;
        const int r  = q / 3;
        const int o  = q - r*3;
        float acc = sW3[24 + o];
#pragma unroll
        for (int f = 0; f < 8; ++f)
            acc = fmaf(H2b[pt*33 + r*8 + f], sW3[f*3 + o], acc);
        const float wv = dwin[(base + pt)*3 + o];
        out[(size_t)base*12 + g] = wv + acc;
    }
}

extern "C" void kernel_launch(void* const* d_in, const int* in_sizes, int n_in,
                              void* d_out, int out_size, void* d_ws, size_t ws_size,
                              hipStream_t stream) {
    const float* qcf   = (const float*)d_in[0];
    const int*   didx  = (const int*)  d_in[1];
    const float* dwin  = (const float*)d_in[2];
    const float* bones = (const float*)d_in[3];
    // d_in[4] = K (always 8)
    const float* Ws = (const float*)d_in[5];
    const float* bs = (const float*)d_in[6];
    const float* W1 = (const float*)d_in[7];
    const float* b1 = (const float*)d_in[8];
    const float* W2 = (const float*)d_in[9];
    const float* b2 = (const float*)d_in[10];
    const float* W3 = (const float*)d_in[11];
    const float* b3 = (const float*)d_in[12];
    float* out = (float*)d_out;

    unsigned short* w1t  = (unsigned short*)d_ws;                    // 8 KB
    unsigned short* w2t  = (unsigned short*)((char*)d_ws + 8192);    // 8 KB
    float*          beff = (float*)((char*)d_ws + 16384);            // 512 B

    hipLaunchKernelGGL(prep_kernel, dim3(33), dim3(256), 0, stream,
                       Ws, bs, W1, b1, W2, w1t, w2t, beff);
    hipLaunchKernelGGL(decoder_kernel, dim3(2048), dim3(256), 0, stream,
                       qcf, didx, dwin, bones, w1t, w2t, beff, b2, W3, b3, out);
}